// Round 5
// baseline (149.966 us; speedup 1.0000x reference)
//
#include <hip/hip_runtime.h>

typedef unsigned short u16;
typedef __attribute__((ext_vector_type(4))) float f32x4;
typedef __attribute__((ext_vector_type(8))) short bf16x8;

#define MFMA16(a,b,c) __builtin_amdgcn_mfma_f32_16x16x32_bf16((a),(b),(c),0,0,0)

__device__ inline u16 f2bf(float f){
  union { float f; unsigned u; } v; v.f = f;
  unsigned r = v.u + 0x7FFFu + ((v.u >> 16) & 1u);
  return (u16)(r >> 16);
}
__device__ inline u16 f2bf_fast(float f){
  union { float f; unsigned u; } v; v.f = f;
  return (u16)((v.u + 0x8000u) >> 16);
}

typedef const __attribute__((address_space(1))) unsigned int* gas_ptr;
typedef __attribute__((address_space(3))) unsigned int* las_ptr;
__device__ inline void gload_lds16(const u16* g, u16* l){
  __builtin_amdgcn_global_load_lds((gas_ptr)(const void*)g, (las_ptr)(void*)l, 16, 0, 0);
}

template<int N>
__device__ inline float rorf(float v){
  union { float f; int i; } a, b; a.f = v;
  b.i = __builtin_amdgcn_update_dpp(a.i, a.i, 0x120|N, 0xF, 0xF, false);
  return b.f;
}
__device__ inline float redMax16(float v){
  v = fmaxf(v, rorf<8>(v)); v = fmaxf(v, rorf<4>(v));
  v = fmaxf(v, rorf<2>(v)); v = fmaxf(v, rorf<1>(v));
  return v;
}

// ---------------- fp32 -> bf16 convert, 3 tensors in one launch ----------------
struct CvtArgs { const float* x[3]; u16* y[3]; };
__global__ void k_cvt3(CvtArgs a, int n4){
  const float* x = a.x[blockIdx.y];
  u16* y = a.y[blockIdx.y];
  int i = blockIdx.x*blockDim.x + threadIdx.x;
  if (i < n4){
    float4 v = ((const float4*)x)[i];
    ushort4 o;
    o.x = f2bf(v.x); o.y = f2bf(v.y); o.z = f2bf(v.z); o.w = f2bf(v.w);
    ((ushort4*)y)[i] = o;
  }
}

// ---------------- W (K x N) fp32 -> Wt (N x K) bf16, 4 weights ----------------
struct TwbArgs { const float* W[4]; u16* Wt[4]; };
__global__ void k_twb4(TwbArgs a){
  __shared__ u16 t[32][33];
  const float* W = a.W[blockIdx.z];
  u16* Wt = a.Wt[blockIdx.z];
  int kb = blockIdx.x*32, nb = blockIdx.y*32;
  int tx = threadIdx.x, ty = threadIdx.y;
  #pragma unroll
  for (int i=0;i<32;i+=8)
    t[ty+i][tx] = f2bf(W[(size_t)(kb+ty+i)*1024 + nb+tx]);
  __syncthreads();
  #pragma unroll
  for (int i=0;i<32;i+=8)
    Wt[(size_t)(nb+ty+i)*1024 + kb+tx] = t[tx][ty+i];
}

// ---------------- QKV projections, 128x128 tile ----------------
// bz==2 (V): write directly to per-head-transposed VT (B,H,DH,T).
struct GemmArgs3 { const u16* A[3]; const u16* Bt[3]; const float* bias[3]; u16* C[3]; };
__global__ __launch_bounds__(256) void k_gemm3(GemmArgs3 g){
  const int N=1024, K=1024;
  int flat = blockIdx.x + (blockIdx.y<<5) + (blockIdx.z<<8);
  int swz = (flat&7)*96 + (flat>>3);
  int by = swz & 7, bx = (swz>>3) & 31, bz = swz >> 8;
  const u16* A = g.A[bz]; const u16* Bt = g.Bt[bz];
  const float* bias = g.bias[bz]; u16* C = g.C[bz];
  __shared__ __attribute__((aligned(16))) u16 As[128*64];
  __shared__ __attribute__((aligned(16))) u16 Bs[128*64];
  const int tid  = threadIdx.x;
  const int wave = tid>>6, lane = tid&63;
  const int lo = lane&15, hi = lane>>4;
  const int row0 = bx*128, col0 = by*128;
  const int wm = (wave>>1)*64, wn = (wave&1)*64;
  f32x4 acc[4][4];
  #pragma unroll
  for (int i=0;i<4;i++)
    #pragma unroll
    for (int j=0;j<4;j++) acc[i][j] = (f32x4){0.f,0.f,0.f,0.f};

  for (int k0=0; k0<K; k0+=64){
    #pragma unroll
    for (int r=0;r<4;r++){
      int c = r*256 + tid;
      gload_lds16(A  + (size_t)(row0 + (c>>3))*K + k0 + (c&7)*8, As + c*8);
      gload_lds16(Bt + (size_t)(col0 + (c>>3))*K + k0 + (c&7)*8, Bs + c*8);
    }
    __syncthreads();
    __builtin_amdgcn_s_setprio(1);
    #pragma unroll
    for (int ks=0;ks<2;ks++){
      bf16x8 af[4], bfr[4];
      #pragma unroll
      for (int mf=0;mf<4;mf++)
        af[mf] = *(const bf16x8*)(As + (wm+mf*16+lo)*64 + ks*32 + hi*8);
      #pragma unroll
      for (int nf=0;nf<4;nf++)
        bfr[nf] = *(const bf16x8*)(Bs + (wn+nf*16+lo)*64 + ks*32 + hi*8);
      #pragma unroll
      for (int mf=0;mf<4;mf++)
        #pragma unroll
        for (int nf=0;nf<4;nf++)
          acc[mf][nf] = MFMA16(af[mf], bfr[nf], acc[mf][nf]);
    }
    __builtin_amdgcn_s_setprio(0);
    __syncthreads();
  }
  if (bz == 2){
    // V: write VT[(b*16+h)*64+dh][t], 4 consecutive t per (mf,nf) -> ushort4
    #pragma unroll
    for (int mf=0;mf<4;mf++){
      #pragma unroll
      for (int nf=0;nf<4;nf++){
        int c0 = col0 + wn + nf*16 + lo;      // global d
        int hh = c0>>6, dh = c0&63;
        int r0 = row0 + wm + mf*16 + hi*4;    // global row (b*T+t)
        int bb = r0>>11, tt = r0&2047;
        float bv = bias[c0];
        ushort4 pk;
        pk.x = f2bf(acc[mf][nf][0]+bv);
        pk.y = f2bf(acc[mf][nf][1]+bv);
        pk.z = f2bf(acc[mf][nf][2]+bv);
        pk.w = f2bf(acc[mf][nf][3]+bv);
        *(ushort4*)(C + ((size_t)((bb*16+hh)*64+dh))*2048 + tt) = pk;
      }
    }
  } else {
    #pragma unroll
    for (int mf=0;mf<4;mf++){
      #pragma unroll
      for (int nf=0;nf<4;nf++){
        int r0 = row0 + wm + mf*16 + hi*4;
        int c0 = col0 + wn + nf*16 + lo;
        float bv = bias[c0];
        #pragma unroll
        for (int r=0;r<4;r++)
          C[(size_t)(r0+r)*N + c0] = f2bf(acc[mf][nf][r] + bv);
      }
    }
  }
}

// ---------------- O projection: 64x128 tiles, 512 blocks (2/CU) ----------------
__global__ __launch_bounds__(256) void k_gemmO(const u16* __restrict__ A, const u16* __restrict__ Bt,
                                               const float* __restrict__ bias, float* __restrict__ C){
  const int N=1024, K=1024;
  int f = blockIdx.x;
  int xcd = f & 7, idx = f >> 3;
  int bx = xcd*8 + (idx>>3), by = idx & 7;   // row-stripe per XCD
  __shared__ __attribute__((aligned(16))) u16 As[64*64];
  __shared__ __attribute__((aligned(16))) u16 Bs[128*64];
  const int tid  = threadIdx.x;
  const int wave = tid>>6, lane = tid&63;
  const int lo = lane&15, hi = lane>>4;
  const int row0 = bx*64, col0 = by*128;
  const int wm = (wave>>1)*32, wn = (wave&1)*64;
  f32x4 acc[2][4];
  #pragma unroll
  for (int i=0;i<2;i++)
    #pragma unroll
    for (int j=0;j<4;j++) acc[i][j] = (f32x4){0.f,0.f,0.f,0.f};

  for (int k0=0; k0<K; k0+=64){
    #pragma unroll
    for (int r=0;r<2;r++){
      int c = r*256 + tid;
      gload_lds16(A + (size_t)(row0 + (c>>3))*K + k0 + (c&7)*8, As + c*8);
    }
    #pragma unroll
    for (int r=0;r<4;r++){
      int c = r*256 + tid;
      gload_lds16(Bt + (size_t)(col0 + (c>>3))*K + k0 + (c&7)*8, Bs + c*8);
    }
    __syncthreads();
    __builtin_amdgcn_s_setprio(1);
    #pragma unroll
    for (int ks=0;ks<2;ks++){
      bf16x8 af[2], bfr[4];
      #pragma unroll
      for (int mf=0;mf<2;mf++)
        af[mf] = *(const bf16x8*)(As + (wm+mf*16+lo)*64 + ks*32 + hi*8);
      #pragma unroll
      for (int nf=0;nf<4;nf++)
        bfr[nf] = *(const bf16x8*)(Bs + (wn+nf*16+lo)*64 + ks*32 + hi*8);
      #pragma unroll
      for (int mf=0;mf<2;mf++)
        #pragma unroll
        for (int nf=0;nf<4;nf++)
          acc[mf][nf] = MFMA16(af[mf], bfr[nf], acc[mf][nf]);
    }
    __builtin_amdgcn_s_setprio(0);
    __syncthreads();
  }
  #pragma unroll
  for (int mf=0;mf<2;mf++){
    #pragma unroll
    for (int nf=0;nf<4;nf++){
      int r0 = row0 + wm + mf*16 + hi*4;
      int c0 = col0 + wn + nf*16 + lo;
      float bv = bias[c0];
      #pragma unroll
      for (int r=0;r<4;r++)
        C[(size_t)(r0+r)*N + c0] = acc[mf][nf][r] + bv;
    }
  }
}

// ---------------- flash attention (causal), v5 ----------------
// 512 blocks x 512 threads (8 waves), 128 q-rows per block; all blocks
// co-resident (3/CU by LDS). Heavy-first (qb2 desc), 4 bh per XCD.
// Lower-half waves skip their fully-masked last tile.
__global__ __launch_bounds__(512) void k_attn(
    const u16* __restrict__ Q, const u16* __restrict__ Kp,
    const u16* __restrict__ VT, u16* __restrict__ O)
{
  const int T=2048, D=1024;
  __shared__ __attribute__((aligned(16))) u16 Ks[2][64*64];
  __shared__ __attribute__((aligned(16))) u16 Vs[2][64*64];
  __shared__ __attribute__((aligned(16))) u16 Plds[8][16*64];
  int f = blockIdx.x;
  int xcd = f & 7, idx = f >> 3;
  const int bh  = (xcd<<2) | (idx&3);
  const int qb2 = 15 - (idx>>2);
  const int b = bh>>4, h = bh&15;
  const int tid = threadIdx.x;
  const int wave = tid>>6, lane = tid&63;
  const int lo = lane&15, hi = lane>>4;
  const float NEG = -__builtin_inff();
  const float sc = 0.125f * 1.44269504f;
  const bf16x8 ones = {0x3F80,0x3F80,0x3F80,0x3F80,0x3F80,0x3F80,0x3F80,0x3F80};

  const int kbmax = 2*qb2 + 1;          // last kv-tile index for this block
  const int kb_d  = 2*qb2 + (wave>>2);  // this wave's diagonal tile

  const int cof0 = ((hi    ) ^ (lo&7))*8;
  const int cof1 = ((hi + 4) ^ (lo&7))*8;

  // staging: 512 chunks of 16B per tensor, 1 chunk per thread
  const int sr = tid>>3, sj = (tid&7)^(sr&7);
  const u16* Kbase = Kp + (size_t)(b*T)*D + h*64;
  const u16* Vbase = VT + (size_t)(bh*64)*T;
  const size_t kOff = (size_t)sr*D + sj*8;
  const size_t vOff = (size_t)sr*T + sj*8;

  const int qrow0 = qb2*128 + wave*16;
  const u16* Qb = Q + (size_t)(b*T + qrow0 + lo)*D + h*64;
  bf16x8 qf0 = *(const bf16x8*)(Qb + hi*8);
  bf16x8 qf1 = *(const bf16x8*)(Qb + 32 + hi*8);

  f32x4 o[4];
  #pragma unroll
  for (int nf=0;nf<4;nf++) o[nf] = (f32x4){0.f,0.f,0.f,0.f};
  float m[4], l[4];
  #pragma unroll
  for (int r=0;r<4;r++){ m[r] = NEG; l[r] = 0.f; }

  gload_lds16(Kbase + kOff, &Ks[0][tid*8]);
  gload_lds16(Vbase + vOff, &Vs[0][tid*8]);
  __syncthreads();

  int cur = 0;
  for (int kb=0; kb<=kbmax; kb++){
    if (kb < kbmax){
      const u16* Kt = Kbase + (size_t)(kb+1)*64*D;
      const u16* Vt = Vbase + (kb+1)*64;
      gload_lds16(Kt + kOff, &Ks[cur^1][tid*8]);
      gload_lds16(Vt + vOff, &Vs[cur^1][tid*8]);
    }
    if (kb <= kb_d){
      const u16* Kl = Ks[cur];
      const u16* Vl = Vs[cur];
      // ---- S = Q K^T (raw units) ----
      f32x4 s[4];
      __builtin_amdgcn_s_setprio(1);
      #pragma unroll
      for (int nf=0;nf<4;nf++){
        int row = nf*16 + lo;
        bf16x8 kf0 = *(const bf16x8*)(Kl + row*64 + cof0);
        bf16x8 kf1 = *(const bf16x8*)(Kl + row*64 + cof1);
        f32x4 z = (f32x4){0.f,0.f,0.f,0.f};
        z = MFMA16(qf0, kf0, z);
        s[nf] = MFMA16(qf1, kf1, z);
      }
      __builtin_amdgcn_s_setprio(0);
      // ---- causal mask (diag tile only) + row max ----
      float pm[4] = {NEG,NEG,NEG,NEG};
      if (kb == kb_d){
        #pragma unroll
        for (int nf=0;nf<4;nf++){
          int col = kb*64 + nf*16 + lo;
          #pragma unroll
          for (int r=0;r<4;r++){
            int row = qrow0 + hi*4 + r;
            if (col > row) s[nf][r] = NEG;
            pm[r] = fmaxf(pm[r], s[nf][r]);
          }
        }
      } else {
        #pragma unroll
        for (int nf=0;nf<4;nf++)
          #pragma unroll
          for (int r=0;r<4;r++)
            pm[r] = fmaxf(pm[r], s[nf][r]);
      }
      #pragma unroll
      for (int r=0;r<4;r++) pm[r] = redMax16(pm[r]);
      // ---- defer-rescale (raw threshold 8/sc ~= 44) ----
      bool small = true;
      #pragma unroll
      for (int r=0;r<4;r++) small = small && (pm[r] <= m[r] + 44.f);
      const bool resc = !__all(small);
      float alpha[4];
      if (resc){
        #pragma unroll
        for (int r=0;r<4;r++){
          float mn = fmaxf(m[r], pm[r]);
          alpha[r] = __builtin_amdgcn_exp2f((m[r] - mn)*sc);
          m[r] = mn;
        }
        #pragma unroll
        for (int nf=0;nf<4;nf++)
          #pragma unroll
          for (int r=0;r<4;r++) o[nf][r] *= alpha[r];
      }
      float msc[4];
      #pragma unroll
      for (int r=0;r<4;r++) msc[r] = m[r]*sc;
      // ---- P = exp2(fma(s, sc, -m*sc)) -> bf16 LDS ----
      #pragma unroll
      for (int nf=0;nf<4;nf++)
        #pragma unroll
        for (int r=0;r<4;r++){
          float p = __builtin_amdgcn_exp2f(__builtin_fmaf(s[nf][r], sc, -msc[r]));
          int prow = hi*4+r, pcol = nf*16+lo;
          Plds[wave][prow*64 + (pcol ^ ((prow&7)<<3))] = f2bf_fast(p);
        }
      // ---- O += P V ; l rowsum via ones-MFMA ----
      bf16x8 pa0 = *(const bf16x8*)(&Plds[wave][lo*64 + cof0]);
      bf16x8 pa1 = *(const bf16x8*)(&Plds[wave][lo*64 + cof1]);
      f32x4 lsum = (f32x4){0.f,0.f,0.f,0.f};
      __builtin_amdgcn_s_setprio(1);
      lsum = MFMA16(pa0, ones, lsum);
      lsum = MFMA16(pa1, ones, lsum);
      #pragma unroll
      for (int nf=0;nf<4;nf++){
        int row = nf*16 + lo;
        bf16x8 v0 = *(const bf16x8*)(Vl + row*64 + cof0);
        bf16x8 v1 = *(const bf16x8*)(Vl + row*64 + cof1);
        o[nf] = MFMA16(pa0, v0, o[nf]);
        o[nf] = MFMA16(pa1, v1, o[nf]);
      }
      __builtin_amdgcn_s_setprio(0);
      if (resc){
        #pragma unroll
        for (int r=0;r<4;r++) l[r] = l[r]*alpha[r] + lsum[r];
      } else {
        #pragma unroll
        for (int r=0;r<4;r++) l[r] += lsum[r];
      }
    }
    __syncthreads();
    cur ^= 1;
  }
  #pragma unroll
  for (int nf=0;nf<4;nf++)
    #pragma unroll
    for (int r=0;r<4;r++){
      int row = qrow0 + hi*4 + r;
      O[(size_t)(b*T+row)*D + h*64 + nf*16 + lo] = f2bf_fast(o[nf][r] / l[r]);
    }
}

extern "C" void kernel_launch(void* const* d_in, const int* in_sizes, int n_in,
                              void* d_out, int out_size, void* d_ws, size_t ws_size,
                              hipStream_t stream) {
  const int B=2, T=2048, D=1024;
  const int M = B*T;
  const float* query = (const float*)d_in[0];
  const float* key   = (const float*)d_in[1];
  const float* value = (const float*)d_in[2];
  const float* Wq = (const float*)d_in[3];  const float* bq = (const float*)d_in[4];
  const float* Wk = (const float*)d_in[5];  const float* bk = (const float*)d_in[6];
  const float* Wv = (const float*)d_in[7];  const float* bv = (const float*)d_in[8];
  const float* Wo = (const float*)d_in[9];  const float* bo = (const float*)d_in[10];
  float* out = (float*)d_out;

  char* ws = (char*)d_ws;
  const size_t MB = 1024*1024;
  u16* xq  = (u16*)(ws + 0*MB);
  u16* xk  = (u16*)(ws + 8*MB);
  u16* xv  = (u16*)(ws + 16*MB);
  u16* WqT = (u16*)(ws + 24*MB);
  u16* WkT = (u16*)(ws + 26*MB);
  u16* WvT = (u16*)(ws + 28*MB);
  u16* WoT = (u16*)(ws + 30*MB);
  u16* Qp  = (u16*)(ws + 32*MB);
  u16* Kp  = (u16*)(ws + 40*MB);
  u16* VTp = (u16*)(ws + 56*MB);
  u16* AO  = (u16*)(ws + 64*MB);

  int n4 = M*D/4;
  CvtArgs ca; ca.x[0]=query; ca.x[1]=key; ca.x[2]=value; ca.y[0]=xq; ca.y[1]=xk; ca.y[2]=xv;
  k_cvt3<<<dim3(n4/256, 3), 256, 0, stream>>>(ca, n4);

  TwbArgs ta; ta.W[0]=Wq; ta.W[1]=Wk; ta.W[2]=Wv; ta.W[3]=Wo;
  ta.Wt[0]=WqT; ta.Wt[1]=WkT; ta.Wt[2]=WvT; ta.Wt[3]=WoT;
  k_twb4<<<dim3(32,32,4), dim3(32,8), 0, stream>>>(ta);

  GemmArgs3 ga;
  ga.A[0]=xq; ga.A[1]=xk; ga.A[2]=xv;
  ga.Bt[0]=WqT; ga.Bt[1]=WkT; ga.Bt[2]=WvT;
  ga.bias[0]=bq; ga.bias[1]=bk; ga.bias[2]=bv;
  ga.C[0]=Qp; ga.C[1]=Kp; ga.C[2]=VTp;      // V written transposed per-head
  k_gemm3<<<dim3(32,8,3), 256, 0, stream>>>(ga);

  k_attn<<<512, 512, 0, stream>>>(Qp, Kp, VTp, AO);
  k_gemmO<<<512, 256, 0, stream>>>(AO, WoT, bo, out);
}

// Round 6
// 129.542 us; speedup vs baseline: 1.1577x; 1.1577x over previous
//
#include <hip/hip_runtime.h>

typedef unsigned short u16;
typedef __attribute__((ext_vector_type(4))) float f32x4;
typedef __attribute__((ext_vector_type(8))) short bf16x8;

#define MFMA16(a,b,c) __builtin_amdgcn_mfma_f32_16x16x32_bf16((a),(b),(c),0,0,0)

__device__ inline u16 f2bf(float f){
  union { float f; unsigned u; } v; v.f = f;
  unsigned r = v.u + 0x7FFFu + ((v.u >> 16) & 1u);
  return (u16)(r >> 16);
}
__device__ inline u16 f2bf_fast(float f){
  union { float f; unsigned u; } v; v.f = f;
  return (u16)((v.u + 0x8000u) >> 16);
}

typedef const __attribute__((address_space(1))) unsigned int* gas_ptr;
typedef __attribute__((address_space(3))) unsigned int* las_ptr;
__device__ inline void gload_lds16(const u16* g, u16* l){
  __builtin_amdgcn_global_load_lds((gas_ptr)(const void*)g, (las_ptr)(void*)l, 16, 0, 0);
}

template<int N>
__device__ inline float rorf(float v){
  union { float f; int i; } a, b; a.f = v;
  b.i = __builtin_amdgcn_update_dpp(a.i, a.i, 0x120|N, 0xF, 0xF, false);
  return b.f;
}
__device__ inline float redMax16(float v){
  v = fmaxf(v, rorf<8>(v)); v = fmaxf(v, rorf<4>(v));
  v = fmaxf(v, rorf<2>(v)); v = fmaxf(v, rorf<1>(v));
  return v;
}

// ---------------- fp32 -> bf16 convert, 3 tensors in one launch ----------------
struct CvtArgs { const float* x[3]; u16* y[3]; };
__global__ void k_cvt3(CvtArgs a, int n4){
  const float* x = a.x[blockIdx.y];
  u16* y = a.y[blockIdx.y];
  int i = blockIdx.x*blockDim.x + threadIdx.x;
  if (i < n4){
    float4 v = ((const float4*)x)[i];
    ushort4 o;
    o.x = f2bf(v.x); o.y = f2bf(v.y); o.z = f2bf(v.z); o.w = f2bf(v.w);
    ((ushort4*)y)[i] = o;
  }
}

// ---------------- W (K x N) fp32 -> Wt (N x K) bf16, 4 weights ----------------
struct TwbArgs { const float* W[4]; u16* Wt[4]; };
__global__ void k_twb4(TwbArgs a){
  __shared__ u16 t[32][33];
  const float* W = a.W[blockIdx.z];
  u16* Wt = a.Wt[blockIdx.z];
  int kb = blockIdx.x*32, nb = blockIdx.y*32;
  int tx = threadIdx.x, ty = threadIdx.y;
  #pragma unroll
  for (int i=0;i<32;i+=8)
    t[ty+i][tx] = f2bf(W[(size_t)(kb+ty+i)*1024 + nb+tx]);
  __syncthreads();
  #pragma unroll
  for (int i=0;i<32;i+=8)
    Wt[(size_t)(nb+ty+i)*1024 + kb+tx] = t[tx][ty+i];
}

// ---------------- V (B*T, D) bf16 -> VT (B,H,DH,T) bf16 ----------------
__global__ void k_tv(const u16* __restrict__ V, u16* __restrict__ VT){
  __shared__ u16 t[32][33];
  int tb = blockIdx.x*32;
  int db = blockIdx.y*32;
  int bh = blockIdx.z;
  int b = bh>>4, h = bh&15;
  int tx = threadIdx.x, ty = threadIdx.y;
  #pragma unroll
  for (int i=0;i<32;i+=8)
    t[ty+i][tx] = V[(size_t)(b*2048 + tb+ty+i)*1024 + h*64 + db+tx];
  __syncthreads();
  #pragma unroll
  for (int i=0;i<32;i+=8)
    VT[(size_t)(bh*64 + db+ty+i)*2048 + tb+tx] = t[tx][ty+i];
}

// ---------------- QKV projections, 128x128 tile, coalesced bf16 epilogue ----------------
struct GemmArgs3 { const u16* A[3]; const u16* Bt[3]; const float* bias[3]; u16* C[3]; };
__global__ __launch_bounds__(256) void k_gemm3(GemmArgs3 g){
  const int N=1024, K=1024;
  int flat = blockIdx.x + (blockIdx.y<<5) + (blockIdx.z<<8);
  int swz = (flat&7)*96 + (flat>>3);
  int by = swz & 7, bx = (swz>>3) & 31, bz = swz >> 8;
  const u16* A = g.A[bz]; const u16* Bt = g.Bt[bz];
  const float* bias = g.bias[bz]; u16* C = g.C[bz];
  __shared__ __attribute__((aligned(16))) u16 As[128*64];
  __shared__ __attribute__((aligned(16))) u16 Bs[128*64];
  const int tid  = threadIdx.x;
  const int wave = tid>>6, lane = tid&63;
  const int lo = lane&15, hi = lane>>4;
  const int row0 = bx*128, col0 = by*128;
  const int wm = (wave>>1)*64, wn = (wave&1)*64;
  f32x4 acc[4][4];
  #pragma unroll
  for (int i=0;i<4;i++)
    #pragma unroll
    for (int j=0;j<4;j++) acc[i][j] = (f32x4){0.f,0.f,0.f,0.f};

  for (int k0=0; k0<K; k0+=64){
    #pragma unroll
    for (int r=0;r<4;r++){
      int c = r*256 + tid;
      gload_lds16(A  + (size_t)(row0 + (c>>3))*K + k0 + (c&7)*8, As + c*8);
      gload_lds16(Bt + (size_t)(col0 + (c>>3))*K + k0 + (c&7)*8, Bs + c*8);
    }
    __syncthreads();
    __builtin_amdgcn_s_setprio(1);
    #pragma unroll
    for (int ks=0;ks<2;ks++){
      bf16x8 af[4], bfr[4];
      #pragma unroll
      for (int mf=0;mf<4;mf++)
        af[mf] = *(const bf16x8*)(As + (wm+mf*16+lo)*64 + ks*32 + hi*8);
      #pragma unroll
      for (int nf=0;nf<4;nf++)
        bfr[nf] = *(const bf16x8*)(Bs + (wn+nf*16+lo)*64 + ks*32 + hi*8);
      #pragma unroll
      for (int mf=0;mf<4;mf++)
        #pragma unroll
        for (int nf=0;nf<4;nf++)
          acc[mf][nf] = MFMA16(af[mf], bfr[nf], acc[mf][nf]);
    }
    __builtin_amdgcn_s_setprio(0);
    __syncthreads();
  }
  #pragma unroll
  for (int mf=0;mf<4;mf++){
    #pragma unroll
    for (int nf=0;nf<4;nf++){
      int r0 = row0 + wm + mf*16 + hi*4;
      int c0 = col0 + wn + nf*16 + lo;
      float bv = bias[c0];
      #pragma unroll
      for (int r=0;r<4;r++)
        C[(size_t)(r0+r)*N + c0] = f2bf(acc[mf][nf][r] + bv);
    }
  }
}

// ---------------- O projection: 64x128 tiles, 512 blocks (2/CU) ----------------
__global__ __launch_bounds__(256) void k_gemmO(const u16* __restrict__ A, const u16* __restrict__ Bt,
                                               const float* __restrict__ bias, float* __restrict__ C){
  const int N=1024, K=1024;
  int f = blockIdx.x;
  int xcd = f & 7, idx = f >> 3;
  int bx = xcd*8 + (idx>>3), by = idx & 7;   // row-stripe per XCD
  __shared__ __attribute__((aligned(16))) u16 As[64*64];
  __shared__ __attribute__((aligned(16))) u16 Bs[128*64];
  const int tid  = threadIdx.x;
  const int wave = tid>>6, lane = tid&63;
  const int lo = lane&15, hi = lane>>4;
  const int row0 = bx*64, col0 = by*128;
  const int wm = (wave>>1)*32, wn = (wave&1)*64;
  f32x4 acc[2][4];
  #pragma unroll
  for (int i=0;i<2;i++)
    #pragma unroll
    for (int j=0;j<4;j++) acc[i][j] = (f32x4){0.f,0.f,0.f,0.f};

  for (int k0=0; k0<K; k0+=64){
    #pragma unroll
    for (int r=0;r<2;r++){
      int c = r*256 + tid;
      gload_lds16(A + (size_t)(row0 + (c>>3))*K + k0 + (c&7)*8, As + c*8);
    }
    #pragma unroll
    for (int r=0;r<4;r++){
      int c = r*256 + tid;
      gload_lds16(Bt + (size_t)(col0 + (c>>3))*K + k0 + (c&7)*8, Bs + c*8);
    }
    __syncthreads();
    __builtin_amdgcn_s_setprio(1);
    #pragma unroll
    for (int ks=0;ks<2;ks++){
      bf16x8 af[2], bfr[4];
      #pragma unroll
      for (int mf=0;mf<2;mf++)
        af[mf] = *(const bf16x8*)(As + (wm+mf*16+lo)*64 + ks*32 + hi*8);
      #pragma unroll
      for (int nf=0;nf<4;nf++)
        bfr[nf] = *(const bf16x8*)(Bs + (wn+nf*16+lo)*64 + ks*32 + hi*8);
      #pragma unroll
      for (int mf=0;mf<2;mf++)
        #pragma unroll
        for (int nf=0;nf<4;nf++)
          acc[mf][nf] = MFMA16(af[mf], bfr[nf], acc[mf][nf]);
    }
    __builtin_amdgcn_s_setprio(0);
    __syncthreads();
  }
  #pragma unroll
  for (int mf=0;mf<2;mf++){
    #pragma unroll
    for (int nf=0;nf<4;nf++){
      int r0 = row0 + wm + mf*16 + hi*4;
      int c0 = col0 + wn + nf*16 + lo;
      float bv = bias[c0];
      #pragma unroll
      for (int r=0;r<4;r++)
        C[(size_t)(r0+r)*N + c0] = acc[mf][nf][r] + bv;
    }
  }
}

// ---------------- flash attention (causal), v4 (proven 55.7us) ----------------
// grid (32,32) = 1024 blocks, one 64-row q-tile each; heavy-first (qb desc)
// dispatch for LPT balance; 4 bh per XCD for L2 KV locality. 4 blocks/CU.
__global__ __launch_bounds__(256) void k_attn(
    const u16* __restrict__ Q, const u16* __restrict__ Kp,
    const u16* __restrict__ VT, u16* __restrict__ O)
{
  const int T=2048, D=1024;
  __shared__ __attribute__((aligned(16))) u16 Ks[2][64*64];
  __shared__ __attribute__((aligned(16))) u16 Vs[2][64*64];
  __shared__ __attribute__((aligned(16))) u16 Plds[4][16*64];
  int f = blockIdx.x + (blockIdx.y<<5);
  int xcd = f & 7, idx = f >> 3;
  const int bh = (xcd<<2) | (idx&3);
  const int qb = 31 - (idx>>2);
  const int b = bh>>4, h = bh&15;
  const int tid = threadIdx.x;
  const int wave = tid>>6, lane = tid&63;
  const int lo = lane&15, hi = lane>>4;
  const float NEG = -__builtin_inff();
  const float sc = 0.125f * 1.44269504f;
  const bf16x8 ones = {0x3F80,0x3F80,0x3F80,0x3F80,0x3F80,0x3F80,0x3F80,0x3F80};

  const int cof0 = ((hi    ) ^ (lo&7))*8;
  const int cof1 = ((hi + 4) ^ (lo&7))*8;

  const int c0 = tid, c1 = 256 + tid;
  const int sr0 = c0>>3, sj0 = (c0&7)^(sr0&7);
  const int sr1 = c1>>3, sj1 = (c1&7)^(sr1&7);
  const u16* Kbase = Kp + (size_t)(b*T)*D + h*64;
  const u16* Vbase = VT + (size_t)(bh*64)*T;
  const size_t kOff0 = (size_t)sr0*D + sj0*8, kOff1 = (size_t)sr1*D + sj1*8;
  const size_t vOff0 = (size_t)sr0*T + sj0*8, vOff1 = (size_t)sr1*T + sj1*8;

  const int qrow0 = qb*64 + wave*16;
  const u16* Qb = Q + (size_t)(b*T + qrow0 + lo)*D + h*64;
  bf16x8 qf0 = *(const bf16x8*)(Qb + hi*8);
  bf16x8 qf1 = *(const bf16x8*)(Qb + 32 + hi*8);

  f32x4 o[4];
  #pragma unroll
  for (int nf=0;nf<4;nf++) o[nf] = (f32x4){0.f,0.f,0.f,0.f};
  float m[4], l[4];
  #pragma unroll
  for (int r=0;r<4;r++){ m[r] = NEG; l[r] = 0.f; }

  gload_lds16(Kbase + kOff0, &Ks[0][c0*8]);
  gload_lds16(Kbase + kOff1, &Ks[0][c1*8]);
  gload_lds16(Vbase + vOff0, &Vs[0][c0*8]);
  gload_lds16(Vbase + vOff1, &Vs[0][c1*8]);
  __syncthreads();

  int cur = 0;
  for (int kb=0; kb<=qb; kb++){
    if (kb < qb){
      const u16* Kt = Kbase + (size_t)(kb+1)*64*D;
      const u16* Vt = Vbase + (kb+1)*64;
      gload_lds16(Kt + kOff0, &Ks[cur^1][c0*8]);
      gload_lds16(Kt + kOff1, &Ks[cur^1][c1*8]);
      gload_lds16(Vt + vOff0, &Vs[cur^1][c0*8]);
      gload_lds16(Vt + vOff1, &Vs[cur^1][c1*8]);
    }
    const u16* Kl = Ks[cur];
    const u16* Vl = Vs[cur];
    // ---- S = Q K^T (raw units) ----
    f32x4 s[4];
    __builtin_amdgcn_s_setprio(1);
    #pragma unroll
    for (int nf=0;nf<4;nf++){
      int row = nf*16 + lo;
      bf16x8 kf0 = *(const bf16x8*)(Kl + row*64 + cof0);
      bf16x8 kf1 = *(const bf16x8*)(Kl + row*64 + cof1);
      f32x4 z = (f32x4){0.f,0.f,0.f,0.f};
      z = MFMA16(qf0, kf0, z);
      s[nf] = MFMA16(qf1, kf1, z);
    }
    __builtin_amdgcn_s_setprio(0);
    // ---- causal mask (diag only) + row max ----
    float pm[4] = {NEG,NEG,NEG,NEG};
    if (kb == qb){
      #pragma unroll
      for (int nf=0;nf<4;nf++){
        int col = kb*64 + nf*16 + lo;
        #pragma unroll
        for (int r=0;r<4;r++){
          int row = qrow0 + hi*4 + r;
          if (col > row) s[nf][r] = NEG;
          pm[r] = fmaxf(pm[r], s[nf][r]);
        }
      }
    } else {
      #pragma unroll
      for (int nf=0;nf<4;nf++)
        #pragma unroll
        for (int r=0;r<4;r++)
          pm[r] = fmaxf(pm[r], s[nf][r]);
    }
    #pragma unroll
    for (int r=0;r<4;r++) pm[r] = redMax16(pm[r]);
    // ---- defer-rescale: raw threshold 8/sc ~= 44 ----
    bool small = true;
    #pragma unroll
    for (int r=0;r<4;r++) small = small && (pm[r] <= m[r] + 44.f);
    const bool resc = !__all(small);
    float alpha[4];
    if (resc){
      #pragma unroll
      for (int r=0;r<4;r++){
        float mn = fmaxf(m[r], pm[r]);
        alpha[r] = __builtin_amdgcn_exp2f((m[r] - mn)*sc);
        m[r] = mn;
      }
      #pragma unroll
      for (int nf=0;nf<4;nf++)
        #pragma unroll
        for (int r=0;r<4;r++) o[nf][r] *= alpha[r];
    }
    float msc[4];
    #pragma unroll
    for (int r=0;r<4;r++) msc[r] = m[r]*sc;
    // ---- P = exp2(fma(s, sc, -m*sc)), store bf16 to LDS ----
    #pragma unroll
    for (int nf=0;nf<4;nf++)
      #pragma unroll
      for (int r=0;r<4;r++){
        float p = __builtin_amdgcn_exp2f(__builtin_fmaf(s[nf][r], sc, -msc[r]));
        int prow = hi*4+r, pcol = nf*16+lo;
        Plds[wave][prow*64 + (pcol ^ ((prow&7)<<3))] = f2bf_fast(p);
      }
    // ---- O += P V ; l rowsum via ones-MFMA ----
    bf16x8 pa0 = *(const bf16x8*)(&Plds[wave][lo*64 + cof0]);
    bf16x8 pa1 = *(const bf16x8*)(&Plds[wave][lo*64 + cof1]);
    f32x4 lsum = (f32x4){0.f,0.f,0.f,0.f};
    __builtin_amdgcn_s_setprio(1);
    lsum = MFMA16(pa0, ones, lsum);
    lsum = MFMA16(pa1, ones, lsum);
    #pragma unroll
    for (int nf=0;nf<4;nf++){
      int row = nf*16 + lo;
      bf16x8 v0 = *(const bf16x8*)(Vl + row*64 + cof0);
      bf16x8 v1 = *(const bf16x8*)(Vl + row*64 + cof1);
      o[nf] = MFMA16(pa0, v0, o[nf]);
      o[nf] = MFMA16(pa1, v1, o[nf]);
    }
    __builtin_amdgcn_s_setprio(0);
    if (resc){
      #pragma unroll
      for (int r=0;r<4;r++) l[r] = l[r]*alpha[r] + lsum[r];
    } else {
      #pragma unroll
      for (int r=0;r<4;r++) l[r] += lsum[r];
    }
    __syncthreads();
    cur ^= 1;
  }
  #pragma unroll
  for (int nf=0;nf<4;nf++)
    #pragma unroll
    for (int r=0;r<4;r++){
      int row = qrow0 + hi*4 + r;
      O[(size_t)(b*T+row)*D + h*64 + nf*16 + lo] = f2bf_fast(o[nf][r] / l[r]);
    }
}

extern "C" void kernel_launch(void* const* d_in, const int* in_sizes, int n_in,
                              void* d_out, int out_size, void* d_ws, size_t ws_size,
                              hipStream_t stream) {
  const int B=2, T=2048, D=1024;
  const int M = B*T;
  const float* query = (const float*)d_in[0];
  const float* key   = (const float*)d_in[1];
  const float* value = (const float*)d_in[2];
  const float* Wq = (const float*)d_in[3];  const float* bq = (const float*)d_in[4];
  const float* Wk = (const float*)d_in[5];  const float* bk = (const float*)d_in[6];
  const float* Wv = (const float*)d_in[7];  const float* bv = (const float*)d_in[8];
  const float* Wo = (const float*)d_in[9];  const float* bo = (const float*)d_in[10];
  float* out = (float*)d_out;

  char* ws = (char*)d_ws;
  const size_t MB = 1024*1024;
  u16* xq  = (u16*)(ws + 0*MB);
  u16* xk  = (u16*)(ws + 8*MB);
  u16* xv  = (u16*)(ws + 16*MB);
  u16* WqT = (u16*)(ws + 24*MB);
  u16* WkT = (u16*)(ws + 26*MB);
  u16* WvT = (u16*)(ws + 28*MB);
  u16* WoT = (u16*)(ws + 30*MB);
  u16* Qp  = (u16*)(ws + 32*MB);
  u16* Kp  = (u16*)(ws + 40*MB);
  u16* Vp  = (u16*)(ws + 48*MB);
  u16* VTp = (u16*)(ws + 56*MB);
  u16* AO  = (u16*)(ws + 64*MB);

  int n4 = M*D/4;
  CvtArgs ca; ca.x[0]=query; ca.x[1]=key; ca.x[2]=value; ca.y[0]=xq; ca.y[1]=xk; ca.y[2]=xv;
  k_cvt3<<<dim3(n4/256, 3), 256, 0, stream>>>(ca, n4);

  TwbArgs ta; ta.W[0]=Wq; ta.W[1]=Wk; ta.W[2]=Wv; ta.W[3]=Wo;
  ta.Wt[0]=WqT; ta.Wt[1]=WkT; ta.Wt[2]=WvT; ta.Wt[3]=WoT;
  k_twb4<<<dim3(32,32,4), dim3(32,8), 0, stream>>>(ta);

  GemmArgs3 ga;
  ga.A[0]=xq; ga.A[1]=xk; ga.A[2]=xv;
  ga.Bt[0]=WqT; ga.Bt[1]=WkT; ga.Bt[2]=WvT;
  ga.bias[0]=bq; ga.bias[1]=bk; ga.bias[2]=bv;
  ga.C[0]=Qp; ga.C[1]=Kp; ga.C[2]=Vp;
  k_gemm3<<<dim3(32,8,3), 256, 0, stream>>>(ga);

  k_tv<<<dim3(T/32, 2, 32), dim3(32,8), 0, stream>>>(Vp, VTp);
  k_attn<<<dim3(32,32), 256, 0, stream>>>(Qp, Kp, VTp, AO);
  k_gemmO<<<512, 256, 0, stream>>>(AO, WoT, bo, out);
}